// Round 1
// baseline (772.636 us; speedup 1.0000x reference)
//
#include <hip/hip_runtime.h>
#include <stdint.h>

typedef float f32x4 __attribute__((ext_vector_type(4)));
typedef int   v4i   __attribute__((ext_vector_type(4)));
typedef int   v8i   __attribute__((ext_vector_type(8)));

#define NROWS 8192
#define DIM   1024
#define BK    128
#define NKT   (DIM / BK)   // 8
#define MARGIN 0.3f
#define SCALE1 0x7F        // e8m0 scale byte: 2^(127-127) = 1.0

// async global->LDS, 16B per lane; LDS dest = wave-uniform base + lane*16
#define GLOAD_LDS16(gp, lp)                                                    \
  __builtin_amdgcn_global_load_lds(                                            \
      (const __attribute__((address_space(1))) void*)(gp),                     \
      (__attribute__((address_space(3))) void*)(lp), 16, 0, 0)

// fp32 [8192*1024] -> fp8 e4m3 (OCP, v_cvt_pk_fp8_f32); 16 elems/thread.
// Also zeroes the scalar output.  (verified correct R6-R8: absmax 0.0)
__global__ __launch_bounds__(256) void cvt_f32_fp8(const float* __restrict__ in,
                                                   uint8_t* __restrict__ out,
                                                   float* __restrict__ loss) {
  if (blockIdx.x == 0 && threadIdx.x == 0) loss[0] = 0.0f;
  size_t i = ((size_t)blockIdx.x * 256 + threadIdx.x) * 16;
  float4 v0 = *(const float4*)(in + i);
  float4 v1 = *(const float4*)(in + i + 4);
  float4 v2 = *(const float4*)(in + i + 8);
  float4 v3 = *(const float4*)(in + i + 12);
  int w0 = 0, w1 = 0, w2 = 0, w3 = 0;
  w0 = __builtin_amdgcn_cvt_pk_fp8_f32(v0.x, v0.y, w0, false);
  w0 = __builtin_amdgcn_cvt_pk_fp8_f32(v0.z, v0.w, w0, true);
  w1 = __builtin_amdgcn_cvt_pk_fp8_f32(v1.x, v1.y, w1, false);
  w1 = __builtin_amdgcn_cvt_pk_fp8_f32(v1.z, v1.w, w1, true);
  w2 = __builtin_amdgcn_cvt_pk_fp8_f32(v2.x, v2.y, w2, false);
  w2 = __builtin_amdgcn_cvt_pk_fp8_f32(v2.z, v2.w, w2, true);
  w3 = __builtin_amdgcn_cvt_pk_fp8_f32(v3.x, v3.y, w3, false);
  w3 = __builtin_amdgcn_cvt_pk_fp8_f32(v3.z, v3.w, w3, true);
  uint4 p; p.x = (unsigned)w0; p.y = (unsigned)w1; p.z = (unsigned)w2; p.w = (unsigned)w3;
  *(uint4*)(out + i) = p;
}

// One block = one 128x128 tile of sim = A*A^T (upper triangle, bi<=bj).
// R10: MX-scaled fp8 path.  mfma_scale_f32_16x16x128_f8f6f4 with unit e8m0
// scales (0x7F -> 2^0) runs the matrix pipe at ~4.66 PF vs ~2.2 PF for the
// non-scaled 16x16x32 fp8 op, with bit-identical math (m145->m148 ladder:
// 995 -> 1628 TF on this exact 128^2 structure).  One MFMA consumes the
// whole BK=128 K-tile: each lane reads its 32B k-chunk as two swizzled
// ds_read_b128 (vs 4x ds_read_b64 before), 16 MFMAs per K-tile per wave
// (vs 64).  Staging, XOR-swizzle, barriers, epilogue unchanged (C/D layout
// is shape-determined: col=lane&15, row=(lane>>4)*4+reg).
__global__ __launch_bounds__(256, 3) void gram_loss(const uint8_t* __restrict__ A8,
                                                    const int* __restrict__ targets,
                                                    float* __restrict__ out) {
  __shared__ uint8_t As[128 * 128];   // 16 KB, swizzled [128][8 slots of 16B]
  __shared__ uint8_t Bs[128 * 128];   // 16 KB
  __shared__ int tRow[128];
  __shared__ int tCol[128];
  __shared__ float wsum[4];

  // linear block id -> (bi, bj) with 0 <= bi <= bj < 64  (fp32 guess + exact fixup)
  int t = blockIdx.x;
  int bi = (int)(0.5f * (129.0f - __builtin_sqrtf(129.0f * 129.0f - 8.0f * (float)t)));
  if (bi < 0) bi = 0;
  if (bi > 63) bi = 63;
  while (bi < 63 && ((bi + 1) * (129 - (bi + 1))) / 2 <= t) ++bi;
  while (bi > 0 && (bi * (129 - bi)) / 2 > t) --bi;
  int bj = bi + (t - (bi * (129 - bi)) / 2);

  const int iBase = bi * 128;
  const int jBase = bj * 128;

  const int tid  = threadIdx.x;
  const int wave = tid >> 6;
  const int lane = tid & 63;

  if (tid < 128) tRow[tid] = targets[iBase + tid];
  else           tCol[tid - 128] = targets[jBase + tid - 128];

  // staging: wave w stages rows [w*32, w*32+32) of both tiles, 4 loads each.
  // one load = 64 lanes x 16B = 8 rows x 128B; lane -> row offset lane>>3,
  // SWIZZLED source col-group (lane&7) ^ (lane>>3)  [row&7 == lane>>3 here
  // since each load covers an 8-row-aligned group].
  const int lrow = lane >> 3;                 // 0..7 == row&7
  const int cg   = (lane & 7) ^ lrow;         // swizzled source col-group
  const uint8_t* gA = A8 + (size_t)(iBase + wave * 32 + lrow) * DIM + cg * 16;
  const uint8_t* gB = A8 + (size_t)(jBase + wave * 32 + lrow) * DIM + cg * 16;
  uint8_t* lA = &As[wave * 32 * 128];
  uint8_t* lB = &Bs[wave * 32 * 128];

  const int m0 = (wave >> 1) * 64;
  const int n0 = (wave & 1) * 64;
  const int fr = lane & 15;    // row within 16-block
  const int r7 = fr & 7;       // swizzle key (rows are 16-aligned per frag)
  // lane's 32B k-chunk = global col-groups {2h, 2h+1}, h = lane>>4.
  // swizzled LDS slot for global group g of row r is g ^ (r&7).
  const int g0  = (lane >> 4) * 2;
  const int co0 = ((g0    ) ^ r7) * 16;
  const int co1 = ((g0 + 1) ^ r7) * 16;

  f32x4 acc[4][4] = {};

  for (int kt = 0; kt < NKT; ++kt) {
    __syncthreads();  // previous tile fully consumed
    const int kOff = kt * BK;
#pragma unroll
    for (int l = 0; l < 4; ++l)
      GLOAD_LDS16(gA + (size_t)(l * 8) * DIM + kOff, lA + l * 8 * 128);
#pragma unroll
    for (int l = 0; l < 4; ++l)
      GLOAD_LDS16(gB + (size_t)(l * 8) * DIM + kOff, lB + l * 8 * 128);
    __syncthreads();  // vmcnt(0) drain + barrier: tile landed

    // one K=128 MFMA pass: lane reads 32B of A/B per fragment row from the
    // two swizzled 16B slots of its k-chunk
    v8i bf[4];
#pragma unroll
    for (int ni = 0; ni < 4; ++ni) {
      const uint8_t* p = &Bs[(n0 + ni * 16 + fr) * 128];
      v4i lo = *(const v4i*)(p + co0);
      v4i hi = *(const v4i*)(p + co1);
      bf[ni] = __builtin_shufflevector(lo, hi, 0, 1, 2, 3, 4, 5, 6, 7);
    }
#pragma unroll
    for (int mi = 0; mi < 4; ++mi) {
      const uint8_t* p = &As[(m0 + mi * 16 + fr) * 128];
      v4i lo = *(const v4i*)(p + co0);
      v4i hi = *(const v4i*)(p + co1);
      v8i af = __builtin_shufflevector(lo, hi, 0, 1, 2, 3, 4, 5, 6, 7);
#pragma unroll
      for (int ni = 0; ni < 4; ++ni)
        acc[mi][ni] = __builtin_amdgcn_mfma_scale_f32_16x16x128_f8f6f4(
            af, bf[ni], acc[mi][ni], 0 /*cbsz: fp8*/, 0 /*blgp: fp8*/,
            0, SCALE1, 0, SCALE1);
    }
  }

  // epilogue: C/D layout col = lane&15, row = (lane>>4)*4 + reg (shape-determined)
  const int col = lane & 15;
  const int rquad = (lane >> 4) * 4;
  float lsum = 0.0f;
#pragma unroll
  for (int ni = 0; ni < 4; ++ni) {
    const int tj = tCol[n0 + ni * 16 + col];
#pragma unroll
    for (int mi = 0; mi < 4; ++mi) {
#pragma unroll
      for (int r = 0; r < 4; ++r) {
        float s = acc[mi][ni][r];
        int ti = tRow[m0 + mi * 16 + rquad + r];
        lsum += (ti == tj) ? (s < 1.0f ? 1.0f - s : 0.0f)
                           : (s > MARGIN ? s : 0.0f);
      }
    }
  }
  if (bi != bj) lsum *= 2.0f;  // symmetric half counted twice

#pragma unroll
  for (int off = 32; off > 0; off >>= 1) lsum += __shfl_down(lsum, off, 64);
  if (lane == 0) wsum[wave] = lsum;
  __syncthreads();
  if (tid == 0)
    atomicAdd(out, (wsum[0] + wsum[1] + wsum[2] + wsum[3]) * (1.0f / (float)NROWS));
}

extern "C" void kernel_launch(void* const* d_in, const int* in_sizes, int n_in,
                              void* d_out, int out_size, void* d_ws, size_t ws_size,
                              hipStream_t stream) {
  const float* x = (const float*)d_in[0];
  const int* targets = (const int*)d_in[1];
  float* out = (float*)d_out;
  uint8_t* x8 = (uint8_t*)d_ws;  // 8192*1024 = 8 MiB scratch

  cvt_f32_fp8<<<2048, 256, 0, stream>>>(x, x8, out);   // 8388608 = 2048*256*16
  gram_loss<<<2080, 256, 0, stream>>>(x8, targets, out);  // 64*65/2 upper-tri blocks
}

// Round 3
// 730.285 us; speedup vs baseline: 1.0580x; 1.0580x over previous
//
#include <hip/hip_runtime.h>
#include <stdint.h>

typedef float f32x4 __attribute__((ext_vector_type(4)));
typedef int   v4i   __attribute__((ext_vector_type(4)));
typedef int   v8i   __attribute__((ext_vector_type(8)));

#define NROWS 8192
#define DIM   1024
#define BK    128
#define NKT   (DIM / BK)   // 8
#define MARGIN 0.3f
#define SCALE1 0x7F        // e8m0 scale byte: 2^(127-127) = 1.0

// async global->LDS, 16B per lane; LDS dest = wave-uniform base + lane*16
#define GLOAD_LDS16(gp, lp)                                                    \
  __builtin_amdgcn_global_load_lds(                                            \
      (const __attribute__((address_space(1))) void*)(gp),                     \
      (__attribute__((address_space(3))) void*)(lp), 16, 0, 0)

// fp32 [8192*1024] -> fp8 e4m3 (OCP, v_cvt_pk_fp8_f32); 16 elems/thread.
// Also zeroes the scalar output.  (verified correct R6-R8: absmax 0.0)
__global__ __launch_bounds__(256) void cvt_f32_fp8(const float* __restrict__ in,
                                                   uint8_t* __restrict__ out,
                                                   float* __restrict__ loss) {
  if (blockIdx.x == 0 && threadIdx.x == 0) loss[0] = 0.0f;
  size_t i = ((size_t)blockIdx.x * 256 + threadIdx.x) * 16;
  float4 v0 = *(const float4*)(in + i);
  float4 v1 = *(const float4*)(in + i + 4);
  float4 v2 = *(const float4*)(in + i + 8);
  float4 v3 = *(const float4*)(in + i + 12);
  int w0 = 0, w1 = 0, w2 = 0, w3 = 0;
  w0 = __builtin_amdgcn_cvt_pk_fp8_f32(v0.x, v0.y, w0, false);
  w0 = __builtin_amdgcn_cvt_pk_fp8_f32(v0.z, v0.w, w0, true);
  w1 = __builtin_amdgcn_cvt_pk_fp8_f32(v1.x, v1.y, w1, false);
  w1 = __builtin_amdgcn_cvt_pk_fp8_f32(v1.z, v1.w, w1, true);
  w2 = __builtin_amdgcn_cvt_pk_fp8_f32(v2.x, v2.y, w2, false);
  w2 = __builtin_amdgcn_cvt_pk_fp8_f32(v2.z, v2.w, w2, true);
  w3 = __builtin_amdgcn_cvt_pk_fp8_f32(v3.x, v3.y, w3, false);
  w3 = __builtin_amdgcn_cvt_pk_fp8_f32(v3.z, v3.w, w3, true);
  uint4 p; p.x = (unsigned)w0; p.y = (unsigned)w1; p.z = (unsigned)w2; p.w = (unsigned)w3;
  *(uint4*)(out + i) = p;
}

// One block = one 128x128 tile of sim = A*A^T (upper triangle, bi<=bj).
// R12 == R11 resubmit (R11 bench was an infra failure, no measurement).
// MX-scaled fp8, spill fix.  R10 was numerically correct but 10x slow:
// WRITE_SIZE 65KB -> 886MB = scratch spill (213 B/thread/K-tile == the
// af+bf operand set).  Cause: full unroll let the scheduler hoist all 16
// fragment ds_reads above the MFMAs -> 64 operand VGPRs live on top of the
// 64-VGPR acc -> blows the launch_bounds(256,3) cap of 168.  Fix: cache
// only bf[4], software-pipeline af one-ahead, and pin with
// sched_barrier(0) after each mi's MFMA cluster so at most 2 A-fragments
// are ever live (~130 regs total).
__global__ __launch_bounds__(256, 3) void gram_loss(const uint8_t* __restrict__ A8,
                                                    const int* __restrict__ targets,
                                                    float* __restrict__ out) {
  __shared__ uint8_t As[128 * 128];   // 16 KB, swizzled [128][8 slots of 16B]
  __shared__ uint8_t Bs[128 * 128];   // 16 KB
  __shared__ int tRow[128];
  __shared__ int tCol[128];
  __shared__ float wsum[4];

  // linear block id -> (bi, bj) with 0 <= bi <= bj < 64  (fp32 guess + exact fixup)
  int t = blockIdx.x;
  int bi = (int)(0.5f * (129.0f - __builtin_sqrtf(129.0f * 129.0f - 8.0f * (float)t)));
  if (bi < 0) bi = 0;
  if (bi > 63) bi = 63;
  while (bi < 63 && ((bi + 1) * (129 - (bi + 1))) / 2 <= t) ++bi;
  while (bi > 0 && (bi * (129 - bi)) / 2 > t) --bi;
  int bj = bi + (t - (bi * (129 - bi)) / 2);

  const int iBase = bi * 128;
  const int jBase = bj * 128;

  const int tid  = threadIdx.x;
  const int wave = tid >> 6;
  const int lane = tid & 63;

  if (tid < 128) tRow[tid] = targets[iBase + tid];
  else           tCol[tid - 128] = targets[jBase + tid - 128];

  // staging: wave w stages rows [w*32, w*32+32) of both tiles, 4 loads each.
  // one load = 64 lanes x 16B = 8 rows x 128B; lane -> row offset lane>>3,
  // SWIZZLED source col-group (lane&7) ^ (lane>>3)  [row&7 == lane>>3 here
  // since each load covers an 8-row-aligned group].
  const int lrow = lane >> 3;                 // 0..7 == row&7
  const int cg   = (lane & 7) ^ lrow;         // swizzled source col-group
  const uint8_t* gA = A8 + (size_t)(iBase + wave * 32 + lrow) * DIM + cg * 16;
  const uint8_t* gB = A8 + (size_t)(jBase + wave * 32 + lrow) * DIM + cg * 16;
  uint8_t* lA = &As[wave * 32 * 128];
  uint8_t* lB = &Bs[wave * 32 * 128];

  const int m0 = (wave >> 1) * 64;
  const int n0 = (wave & 1) * 64;
  const int fr = lane & 15;    // row within 16-block
  const int r7 = fr & 7;       // swizzle key (rows are 16-aligned per frag)
  // lane's 32B k-chunk = global col-groups {2h, 2h+1}, h = lane>>4.
  // swizzled LDS slot for global group g of row r is g ^ (r&7).
  const int g0  = (lane >> 4) * 2;
  const int co0 = ((g0    ) ^ r7) * 16;
  const int co1 = ((g0 + 1) ^ r7) * 16;

  // 32B fragment read from swizzled LDS (two b128 from the lane's k-chunk)
#define LD_FRAG(base_, row_)                                                   \
  ({ const uint8_t* p_ = &(base_)[(row_) * 128];                               \
     v4i lo_ = *(const v4i*)(p_ + co0);                                        \
     v4i hi_ = *(const v4i*)(p_ + co1);                                        \
     __builtin_shufflevector(lo_, hi_, 0, 1, 2, 3, 4, 5, 6, 7); })

  f32x4 acc[4][4] = {};

  for (int kt = 0; kt < NKT; ++kt) {
    __syncthreads();  // previous tile fully consumed
    const int kOff = kt * BK;
#pragma unroll
    for (int l = 0; l < 4; ++l)
      GLOAD_LDS16(gA + (size_t)(l * 8) * DIM + kOff, lA + l * 8 * 128);
#pragma unroll
    for (int l = 0; l < 4; ++l)
      GLOAD_LDS16(gB + (size_t)(l * 8) * DIM + kOff, lB + l * 8 * 128);
    __syncthreads();  // vmcnt(0) drain + barrier: tile landed

    // B fragments cached for the whole tile (32 VGPRs)
    v8i bf[4];
#pragma unroll
    for (int ni = 0; ni < 4; ++ni)
      bf[ni] = LD_FRAG(Bs, n0 + ni * 16 + fr);

    // A fragments pipelined one-ahead; sched_barrier pins each cluster so
    // the scheduler cannot hoist all af loads (the R10 spill).
    v8i afc = LD_FRAG(As, m0 + 0 * 16 + fr);
#pragma unroll
    for (int mi = 0; mi < 4; ++mi) {
      v8i afn = afc;
      if (mi < 3) afn = LD_FRAG(As, m0 + (mi + 1) * 16 + fr);
#pragma unroll
      for (int ni = 0; ni < 4; ++ni)
        acc[mi][ni] = __builtin_amdgcn_mfma_scale_f32_16x16x128_f8f6f4(
            afc, bf[ni], acc[mi][ni], 0 /*cbsz: fp8*/, 0 /*blgp: fp8*/,
            0, SCALE1, 0, SCALE1);
      __builtin_amdgcn_sched_barrier(0);
      afc = afn;
    }
  }
#undef LD_FRAG

  // epilogue: C/D layout col = lane&15, row = (lane>>4)*4 + reg (shape-determined)
  const int col = lane & 15;
  const int rquad = (lane >> 4) * 4;
  float lsum = 0.0f;
#pragma unroll
  for (int ni = 0; ni < 4; ++ni) {
    const int tj = tCol[n0 + ni * 16 + col];
#pragma unroll
    for (int mi = 0; mi < 4; ++mi) {
#pragma unroll
      for (int r = 0; r < 4; ++r) {
        float s = acc[mi][ni][r];
        int ti = tRow[m0 + mi * 16 + rquad + r];
        lsum += (ti == tj) ? (s < 1.0f ? 1.0f - s : 0.0f)
                           : (s > MARGIN ? s : 0.0f);
      }
    }
  }
  if (bi != bj) lsum *= 2.0f;  // symmetric half counted twice

#pragma unroll
  for (int off = 32; off > 0; off >>= 1) lsum += __shfl_down(lsum, off, 64);
  if (lane == 0) wsum[wave] = lsum;
  __syncthreads();
  if (tid == 0)
    atomicAdd(out, (wsum[0] + wsum[1] + wsum[2] + wsum[3]) * (1.0f / (float)NROWS));
}

extern "C" void kernel_launch(void* const* d_in, const int* in_sizes, int n_in,
                              void* d_out, int out_size, void* d_ws, size_t ws_size,
                              hipStream_t stream) {
  const float* x = (const float*)d_in[0];
  const int* targets = (const int*)d_in[1];
  float* out = (float*)d_out;
  uint8_t* x8 = (uint8_t*)d_ws;  // 8192*1024 = 8 MiB scratch

  cvt_f32_fp8<<<2048, 256, 0, stream>>>(x, x8, out);   // 8388608 = 2048*256*16
  gram_loss<<<2080, 256, 0, stream>>>(x8, targets, out);  // 64*65/2 upper-tri blocks
}

// Round 4
// 530.248 us; speedup vs baseline: 1.4571x; 1.3773x over previous
//
#include <hip/hip_runtime.h>
#include <stdint.h>

typedef float f32x16 __attribute__((ext_vector_type(16)));
typedef int   v4i    __attribute__((ext_vector_type(4)));
typedef int   v8i    __attribute__((ext_vector_type(8)));

#define NROWS 8192
#define DIM   1024
#define BK    128
#define NKT   (DIM / BK)   // 8
#define MARGIN 0.3f
#define SCALE1 0x7F        // e8m0 scale byte: 2^(127-127) = 1.0

// async global->LDS, 16B per lane; LDS dest = wave-uniform base + lane*16
#define GLOAD_LDS16(gp, lp)                                                    \
  __builtin_amdgcn_global_load_lds(                                            \
      (const __attribute__((address_space(1))) void*)(gp),                     \
      (__attribute__((address_space(3))) void*)(lp), 16, 0, 0)

// fp32 [8192*1024] -> fp8 e4m3 (OCP, v_cvt_pk_fp8_f32); 16 elems/thread.
// Also zeroes the scalar output.  (verified correct R6-R8: absmax 0.0)
__global__ __launch_bounds__(256) void cvt_f32_fp8(const float* __restrict__ in,
                                                   uint8_t* __restrict__ out,
                                                   float* __restrict__ loss) {
  if (blockIdx.x == 0 && threadIdx.x == 0) loss[0] = 0.0f;
  size_t i = ((size_t)blockIdx.x * 256 + threadIdx.x) * 16;
  float4 v0 = *(const float4*)(in + i);
  float4 v1 = *(const float4*)(in + i + 4);
  float4 v2 = *(const float4*)(in + i + 8);
  float4 v3 = *(const float4*)(in + i + 12);
  int w0 = 0, w1 = 0, w2 = 0, w3 = 0;
  w0 = __builtin_amdgcn_cvt_pk_fp8_f32(v0.x, v0.y, w0, false);
  w0 = __builtin_amdgcn_cvt_pk_fp8_f32(v0.z, v0.w, w0, true);
  w1 = __builtin_amdgcn_cvt_pk_fp8_f32(v1.x, v1.y, w1, false);
  w1 = __builtin_amdgcn_cvt_pk_fp8_f32(v1.z, v1.w, w1, true);
  w2 = __builtin_amdgcn_cvt_pk_fp8_f32(v2.x, v2.y, w2, false);
  w2 = __builtin_amdgcn_cvt_pk_fp8_f32(v2.z, v2.w, w2, true);
  w3 = __builtin_amdgcn_cvt_pk_fp8_f32(v3.x, v3.y, w3, false);
  w3 = __builtin_amdgcn_cvt_pk_fp8_f32(v3.z, v3.w, w3, true);
  uint4 p; p.x = (unsigned)w0; p.y = (unsigned)w1; p.z = (unsigned)w2; p.w = (unsigned)w3;
  *(uint4*)(out + i) = p;
}

// One block = one 128x128 tile of sim = A*A^T (upper triangle, bi<=bj).
// R13: MX fp8 via 32x32x64 (was 16x16x128 in R10/R12, which spilled ~192
// B/thread/K-tile = the 48-VGPR operand set on top of 64 acc regs under the
// launch_bounds(256,3) 168-reg cap; sched pins didn't help).  32x32x64 wave
// tile = 2x2 fragments: only 4 operand fragments (32 VGPRs) live per
// k-step; even a full 2-k-step hoist (64+64 acc+~25 temps=153) fits the cap
// -> spill impossible by construction.  acc as named scalars (no arrays).
// A/B frag: row=lane&31, k in [(lane>>5)*32,+32) (2 swizzled b128 reads).
// C/D layout (m74/m101, dtype-indep): col=lane&31,
// row=(reg&3)+8*(reg>>2)+4*(lane>>5).  Swizzle/staging/barriers unchanged.
__global__ __launch_bounds__(256, 3) void gram_loss(const uint8_t* __restrict__ A8,
                                                    const int* __restrict__ targets,
                                                    float* __restrict__ out) {
  __shared__ uint8_t As[128 * 128];   // 16 KB, swizzled [128][8 slots of 16B]
  __shared__ uint8_t Bs[128 * 128];   // 16 KB
  __shared__ int tRow[128];
  __shared__ int tCol[128];
  __shared__ float wsum[4];

  // linear block id -> (bi, bj) with 0 <= bi <= bj < 64  (fp32 guess + exact fixup)
  int t = blockIdx.x;
  int bi = (int)(0.5f * (129.0f - __builtin_sqrtf(129.0f * 129.0f - 8.0f * (float)t)));
  if (bi < 0) bi = 0;
  if (bi > 63) bi = 63;
  while (bi < 63 && ((bi + 1) * (129 - (bi + 1))) / 2 <= t) ++bi;
  while (bi > 0 && (bi * (129 - bi)) / 2 > t) --bi;
  int bj = bi + (t - (bi * (129 - bi)) / 2);

  const int iBase = bi * 128;
  const int jBase = bj * 128;

  const int tid  = threadIdx.x;
  const int wave = tid >> 6;
  const int lane = tid & 63;

  if (tid < 128) tRow[tid] = targets[iBase + tid];
  else           tCol[tid - 128] = targets[jBase + tid - 128];

  // staging: wave w stages rows [w*32, w*32+32) of both tiles, 4 loads each.
  // one load = 64 lanes x 16B = 8 rows x 128B; lane -> row offset lane>>3,
  // SWIZZLED source col-group (lane&7) ^ (lane>>3)  [row&7 == lane>>3 here
  // since each load covers an 8-row-aligned group].
  const int lrow = lane >> 3;                 // 0..7 == row&7
  const int cg   = (lane & 7) ^ lrow;         // swizzled source col-group
  const uint8_t* gA = A8 + (size_t)(iBase + wave * 32 + lrow) * DIM + cg * 16;
  const uint8_t* gB = A8 + (size_t)(jBase + wave * 32 + lrow) * DIM + cg * 16;
  uint8_t* lA = &As[wave * 32 * 128];
  uint8_t* lB = &Bs[wave * 32 * 128];

  const int m0 = (wave >> 1) * 64;   // wave's 64x64 output tile
  const int n0 = (wave & 1) * 64;
  const int r31 = lane & 31;         // fragment row (A) / col (B)
  const int r7  = r31 & 7;           // swizzle key (m0, mi*32 are 8-aligned)
  const int hp  = lane >> 5;         // 0/1: which 32B k-half of the 64-k step

  // 32B fragment read from swizzled LDS: pre-XOR col-groups {gb, gb+1}
#define LD_FRAG32(base_, row_, gb_)                                            \
  ({ const uint8_t* p_ = &(base_)[(row_) * 128];                               \
     v4i lo_ = *(const v4i*)(p_ + ((((gb_)    ) ^ r7) * 16));                  \
     v4i hi_ = *(const v4i*)(p_ + ((((gb_) + 1) ^ r7) * 16));                  \
     __builtin_shufflevector(lo_, hi_, 0, 1, 2, 3, 4, 5, 6, 7); })

  f32x16 acc00 = {}, acc01 = {}, acc10 = {}, acc11 = {};

  for (int kt = 0; kt < NKT; ++kt) {
    __syncthreads();  // previous tile fully consumed
    const int kOff = kt * BK;
#pragma unroll
    for (int l = 0; l < 4; ++l)
      GLOAD_LDS16(gA + (size_t)(l * 8) * DIM + kOff, lA + l * 8 * 128);
#pragma unroll
    for (int l = 0; l < 4; ++l)
      GLOAD_LDS16(gB + (size_t)(l * 8) * DIM + kOff, lB + l * 8 * 128);
    __syncthreads();  // vmcnt(0) drain + barrier: tile landed

    // two K=64 k-steps; per step 4 fragments (32 VGPRs) live
#pragma unroll
    for (int ks = 0; ks < 2; ++ks) {
      const int gb = ks * 4 + hp * 2;  // this lane's pre-XOR 16B col-group pair
      v8i a0 = LD_FRAG32(As, m0 +      r31, gb);
      v8i a1 = LD_FRAG32(As, m0 + 32 + r31, gb);
      v8i b0 = LD_FRAG32(Bs, n0 +      r31, gb);
      v8i b1 = LD_FRAG32(Bs, n0 + 32 + r31, gb);
      acc00 = __builtin_amdgcn_mfma_scale_f32_32x32x64_f8f6f4(
          a0, b0, acc00, 0, 0, 0, SCALE1, 0, SCALE1);
      acc01 = __builtin_amdgcn_mfma_scale_f32_32x32x64_f8f6f4(
          a0, b1, acc01, 0, 0, 0, SCALE1, 0, SCALE1);
      acc10 = __builtin_amdgcn_mfma_scale_f32_32x32x64_f8f6f4(
          a1, b0, acc10, 0, 0, 0, SCALE1, 0, SCALE1);
      acc11 = __builtin_amdgcn_mfma_scale_f32_32x32x64_f8f6f4(
          a1, b1, acc11, 0, 0, 0, SCALE1, 0, SCALE1);
    }
  }
#undef LD_FRAG32

  // epilogue: 32x32 C/D layout col = lane&31, row = (reg&3)+8*(reg>>2)+4*(lane>>5)
  const int col = r31;
  const int rbase = 4 * hp;
  float lsum = 0.0f;
#define ACC_SUM(acc_, mi_, ni_)                                                \
  { const int tj_ = tCol[n0 + (ni_) * 32 + col];                               \
    _Pragma("unroll")                                                          \
    for (int r = 0; r < 16; ++r) {                                             \
      float s = (acc_)[r];                                                     \
      int row_ = (r & 3) + 8 * (r >> 2) + rbase;                               \
      int ti_ = tRow[m0 + (mi_) * 32 + row_];                                  \
      lsum += (ti_ == tj_) ? (s < 1.0f ? 1.0f - s : 0.0f)                      \
                           : (s > MARGIN ? s : 0.0f);                          \
    } }
  ACC_SUM(acc00, 0, 0)
  ACC_SUM(acc01, 0, 1)
  ACC_SUM(acc10, 1, 0)
  ACC_SUM(acc11, 1, 1)
#undef ACC_SUM
  if (bi != bj) lsum *= 2.0f;  // symmetric half counted twice

#pragma unroll
  for (int off = 32; off > 0; off >>= 1) lsum += __shfl_down(lsum, off, 64);
  if (lane == 0) wsum[wave] = lsum;
  __syncthreads();
  if (tid == 0)
    atomicAdd(out, (wsum[0] + wsum[1] + wsum[2] + wsum[3]) * (1.0f / (float)NROWS));
}

extern "C" void kernel_launch(void* const* d_in, const int* in_sizes, int n_in,
                              void* d_out, int out_size, void* d_ws, size_t ws_size,
                              hipStream_t stream) {
  const float* x = (const float*)d_in[0];
  const int* targets = (const int*)d_in[1];
  float* out = (float*)d_out;
  uint8_t* x8 = (uint8_t*)d_ws;  // 8192*1024 = 8 MiB scratch

  cvt_f32_fp8<<<2048, 256, 0, stream>>>(x, x8, out);   // 8388608 = 2048*256*16
  gram_loss<<<2080, 256, 0, stream>>>(x8, targets, out);  // 64*65/2 upper-tri blocks
}

// Round 5
// 233.294 us; speedup vs baseline: 3.3119x; 2.2729x over previous
//
#include <hip/hip_runtime.h>
#include <stdint.h>

typedef float f32x16 __attribute__((ext_vector_type(16)));
typedef int   v4i    __attribute__((ext_vector_type(4)));
typedef int   v8i    __attribute__((ext_vector_type(8)));

#define NROWS 8192
#define DIM   1024
#define BK    128
#define NKT   (DIM / BK)   // 8
#define MARGIN 0.3f
#define SCALE1 0x7F        // e8m0 scale byte: 2^(127-127) = 1.0

// async global->LDS, 16B per lane; LDS dest = wave-uniform base + lane*16
#define GLOAD_LDS16(gp, lp)                                                    \
  __builtin_amdgcn_global_load_lds(                                            \
      (const __attribute__((address_space(1))) void*)(gp),                     \
      (__attribute__((address_space(3))) void*)(lp), 16, 0, 0)

// fp32 [8192*1024] -> fp8 e4m3 (OCP, v_cvt_pk_fp8_f32); 16 elems/thread.
// Also zeroes the scalar output.  (verified correct R6-R8: absmax 0.0)
__global__ __launch_bounds__(256) void cvt_f32_fp8(const float* __restrict__ in,
                                                   uint8_t* __restrict__ out,
                                                   float* __restrict__ loss) {
  if (blockIdx.x == 0 && threadIdx.x == 0) loss[0] = 0.0f;
  size_t i = ((size_t)blockIdx.x * 256 + threadIdx.x) * 16;
  float4 v0 = *(const float4*)(in + i);
  float4 v1 = *(const float4*)(in + i + 4);
  float4 v2 = *(const float4*)(in + i + 8);
  float4 v3 = *(const float4*)(in + i + 12);
  int w0 = 0, w1 = 0, w2 = 0, w3 = 0;
  w0 = __builtin_amdgcn_cvt_pk_fp8_f32(v0.x, v0.y, w0, false);
  w0 = __builtin_amdgcn_cvt_pk_fp8_f32(v0.z, v0.w, w0, true);
  w1 = __builtin_amdgcn_cvt_pk_fp8_f32(v1.x, v1.y, w1, false);
  w1 = __builtin_amdgcn_cvt_pk_fp8_f32(v1.z, v1.w, w1, true);
  w2 = __builtin_amdgcn_cvt_pk_fp8_f32(v2.x, v2.y, w2, false);
  w2 = __builtin_amdgcn_cvt_pk_fp8_f32(v2.z, v2.w, w2, true);
  w3 = __builtin_amdgcn_cvt_pk_fp8_f32(v3.x, v3.y, w3, false);
  w3 = __builtin_amdgcn_cvt_pk_fp8_f32(v3.z, v3.w, w3, true);
  uint4 p; p.x = (unsigned)w0; p.y = (unsigned)w1; p.z = (unsigned)w2; p.w = (unsigned)w3;
  *(uint4*)(out + i) = p;
}

// One block = one 128x128 tile of sim = A*A^T (upper triangle, bi<=bj).
// R14 == R13 with the occupancy cap REMOVED.  R10/R12/R13 all spilled the
// same ~200 B/thread/K-tile (WRITE_SIZE ~840 MB) regardless of source
// structure -> the spill is not operand-count-driven; it's the
// launch_bounds(256,3) 170-reg cap.  The reference MX kernel (m148, 1628
// TF) compiled to 164 VGPR + 64 AGPR ~ 228 unified regs with NO min-waves
// bound, at 2 waves/SIMD.  The MX K-loop inherently wants ~220 regs; let
// the allocator have them.  LDS 34 KB still allows 4 blocks/CU; registers
// will limit to 2 blocks/CU — m148's proven regime.
// A/B frag: row=lane&31, k in [(lane>>5)*32,+32) (2 swizzled b128 reads).
// C/D layout (m74/m101, dtype-indep): col=lane&31,
// row=(reg&3)+8*(reg>>2)+4*(lane>>5).  Swizzle/staging/barriers unchanged.
__global__ __launch_bounds__(256) void gram_loss(const uint8_t* __restrict__ A8,
                                                 const int* __restrict__ targets,
                                                 float* __restrict__ out) {
  __shared__ uint8_t As[128 * 128];   // 16 KB, swizzled [128][8 slots of 16B]
  __shared__ uint8_t Bs[128 * 128];   // 16 KB
  __shared__ int tRow[128];
  __shared__ int tCol[128];
  __shared__ float wsum[4];

  // linear block id -> (bi, bj) with 0 <= bi <= bj < 64  (fp32 guess + exact fixup)
  int t = blockIdx.x;
  int bi = (int)(0.5f * (129.0f - __builtin_sqrtf(129.0f * 129.0f - 8.0f * (float)t)));
  if (bi < 0) bi = 0;
  if (bi > 63) bi = 63;
  while (bi < 63 && ((bi + 1) * (129 - (bi + 1))) / 2 <= t) ++bi;
  while (bi > 0 && (bi * (129 - bi)) / 2 > t) --bi;
  int bj = bi + (t - (bi * (129 - bi)) / 2);

  const int iBase = bi * 128;
  const int jBase = bj * 128;

  const int tid  = threadIdx.x;
  const int wave = tid >> 6;
  const int lane = tid & 63;

  if (tid < 128) tRow[tid] = targets[iBase + tid];
  else           tCol[tid - 128] = targets[jBase + tid - 128];

  // staging: wave w stages rows [w*32, w*32+32) of both tiles, 4 loads each.
  // one load = 64 lanes x 16B = 8 rows x 128B; lane -> row offset lane>>3,
  // SWIZZLED source col-group (lane&7) ^ (lane>>3)  [row&7 == lane>>3 here
  // since each load covers an 8-row-aligned group].
  const int lrow = lane >> 3;                 // 0..7 == row&7
  const int cg   = (lane & 7) ^ lrow;         // swizzled source col-group
  const uint8_t* gA = A8 + (size_t)(iBase + wave * 32 + lrow) * DIM + cg * 16;
  const uint8_t* gB = A8 + (size_t)(jBase + wave * 32 + lrow) * DIM + cg * 16;
  uint8_t* lA = &As[wave * 32 * 128];
  uint8_t* lB = &Bs[wave * 32 * 128];

  const int m0 = (wave >> 1) * 64;   // wave's 64x64 output tile
  const int n0 = (wave & 1) * 64;
  const int r31 = lane & 31;         // fragment row (A) / col (B)
  const int r7  = r31 & 7;           // swizzle key (m0, mi*32 are 8-aligned)
  const int hp  = lane >> 5;         // 0/1: which 32B k-half of the 64-k step

  // 32B fragment read from swizzled LDS: pre-XOR col-groups {gb, gb+1}
#define LD_FRAG32(base_, row_, gb_)                                            \
  ({ const uint8_t* p_ = &(base_)[(row_) * 128];                               \
     v4i lo_ = *(const v4i*)(p_ + ((((gb_)    ) ^ r7) * 16));                  \
     v4i hi_ = *(const v4i*)(p_ + ((((gb_) + 1) ^ r7) * 16));                  \
     __builtin_shufflevector(lo_, hi_, 0, 1, 2, 3, 4, 5, 6, 7); })

  f32x16 acc00 = {}, acc01 = {}, acc10 = {}, acc11 = {};

  for (int kt = 0; kt < NKT; ++kt) {
    __syncthreads();  // previous tile fully consumed
    const int kOff = kt * BK;
#pragma unroll
    for (int l = 0; l < 4; ++l)
      GLOAD_LDS16(gA + (size_t)(l * 8) * DIM + kOff, lA + l * 8 * 128);
#pragma unroll
    for (int l = 0; l < 4; ++l)
      GLOAD_LDS16(gB + (size_t)(l * 8) * DIM + kOff, lB + l * 8 * 128);
    __syncthreads();  // vmcnt(0) drain + barrier: tile landed

    // two K=64 k-steps; per step 4 fragments (32 VGPRs) live
#pragma unroll
    for (int ks = 0; ks < 2; ++ks) {
      const int gb = ks * 4 + hp * 2;  // this lane's pre-XOR 16B col-group pair
      v8i a0 = LD_FRAG32(As, m0 +      r31, gb);
      v8i a1 = LD_FRAG32(As, m0 + 32 + r31, gb);
      v8i b0 = LD_FRAG32(Bs, n0 +      r31, gb);
      v8i b1 = LD_FRAG32(Bs, n0 + 32 + r31, gb);
      acc00 = __builtin_amdgcn_mfma_scale_f32_32x32x64_f8f6f4(
          a0, b0, acc00, 0, 0, 0, SCALE1, 0, SCALE1);
      acc01 = __builtin_amdgcn_mfma_scale_f32_32x32x64_f8f6f4(
          a0, b1, acc01, 0, 0, 0, SCALE1, 0, SCALE1);
      acc10 = __builtin_amdgcn_mfma_scale_f32_32x32x64_f8f6f4(
          a1, b0, acc10, 0, 0, 0, SCALE1, 0, SCALE1);
      acc11 = __builtin_amdgcn_mfma_scale_f32_32x32x64_f8f6f4(
          a1, b1, acc11, 0, 0, 0, SCALE1, 0, SCALE1);
    }
  }
#undef LD_FRAG32

  // epilogue: 32x32 C/D layout col = lane&31, row = (reg&3)+8*(reg>>2)+4*(lane>>5)
  const int col = r31;
  const int rbase = 4 * hp;
  float lsum = 0.0f;
#define ACC_SUM(acc_, mi_, ni_)                                                \
  { const int tj_ = tCol[n0 + (ni_) * 32 + col];                               \
    _Pragma("unroll")                                                          \
    for (int r = 0; r < 16; ++r) {                                             \
      float s = (acc_)[r];                                                     \
      int row_ = (r & 3) + 8 * (r >> 2) + rbase;                               \
      int ti_ = tRow[m0 + (mi_) * 32 + row_];                                  \
      lsum += (ti_ == tj_) ? (s < 1.0f ? 1.0f - s : 0.0f)                      \
                           : (s > MARGIN ? s : 0.0f);                          \
    } }
  ACC_SUM(acc00, 0, 0)
  ACC_SUM(acc01, 0, 1)
  ACC_SUM(acc10, 1, 0)
  ACC_SUM(acc11, 1, 1)
#undef ACC_SUM
  if (bi != bj) lsum *= 2.0f;  // symmetric half counted twice

#pragma unroll
  for (int off = 32; off > 0; off >>= 1) lsum += __shfl_down(lsum, off, 64);
  if (lane == 0) wsum[wave] = lsum;
  __syncthreads();
  if (tid == 0)
    atomicAdd(out, (wsum[0] + wsum[1] + wsum[2] + wsum[3]) * (1.0f / (float)NROWS));
}

extern "C" void kernel_launch(void* const* d_in, const int* in_sizes, int n_in,
                              void* d_out, int out_size, void* d_ws, size_t ws_size,
                              hipStream_t stream) {
  const float* x = (const float*)d_in[0];
  const int* targets = (const int*)d_in[1];
  float* out = (float*)d_out;
  uint8_t* x8 = (uint8_t*)d_ws;  // 8192*1024 = 8 MiB scratch

  cvt_f32_fp8<<<2048, 256, 0, stream>>>(x, x8, out);   // 8388608 = 2048*256*16
  gram_loss<<<2080, 256, 0, stream>>>(x8, targets, out);  // 64*65/2 upper-tri blocks
}

// Round 6
// 136.246 us; speedup vs baseline: 5.6709x; 1.7123x over previous
//
#include <hip/hip_runtime.h>
#include <stdint.h>

typedef float f32x4 __attribute__((ext_vector_type(4)));

#define NROWS 8192
#define DIM   1024
#define BK    128
#define NKT   (DIM / BK)   // 8
#define MARGIN 0.3f

// async global->LDS, 16B per lane; LDS dest = wave-uniform base + lane*16
#define GLOAD_LDS16(gp, lp)                                                    \
  __builtin_amdgcn_global_load_lds(                                            \
      (const __attribute__((address_space(1))) void*)(gp),                     \
      (__attribute__((address_space(3))) void*)(lp), 16, 0, 0)

// fp32 [8192*1024] -> fp8 e4m3 (OCP, v_cvt_pk_fp8_f32); 16 elems/thread.
// Also zeroes the scalar output.  (verified correct R6-R8: absmax 0.0)
__global__ __launch_bounds__(256) void cvt_f32_fp8(const float* __restrict__ in,
                                                   uint8_t* __restrict__ out,
                                                   float* __restrict__ loss) {
  if (blockIdx.x == 0 && threadIdx.x == 0) loss[0] = 0.0f;
  size_t i = ((size_t)blockIdx.x * 256 + threadIdx.x) * 16;
  float4 v0 = *(const float4*)(in + i);
  float4 v1 = *(const float4*)(in + i + 4);
  float4 v2 = *(const float4*)(in + i + 8);
  float4 v3 = *(const float4*)(in + i + 12);
  int w0 = 0, w1 = 0, w2 = 0, w3 = 0;
  w0 = __builtin_amdgcn_cvt_pk_fp8_f32(v0.x, v0.y, w0, false);
  w0 = __builtin_amdgcn_cvt_pk_fp8_f32(v0.z, v0.w, w0, true);
  w1 = __builtin_amdgcn_cvt_pk_fp8_f32(v1.x, v1.y, w1, false);
  w1 = __builtin_amdgcn_cvt_pk_fp8_f32(v1.z, v1.w, w1, true);
  w2 = __builtin_amdgcn_cvt_pk_fp8_f32(v2.x, v2.y, w2, false);
  w2 = __builtin_amdgcn_cvt_pk_fp8_f32(v2.z, v2.w, w2, true);
  w3 = __builtin_amdgcn_cvt_pk_fp8_f32(v3.x, v3.y, w3, false);
  w3 = __builtin_amdgcn_cvt_pk_fp8_f32(v3.z, v3.w, w3, true);
  uint4 p; p.x = (unsigned)w0; p.y = (unsigned)w1; p.z = (unsigned)w2; p.w = (unsigned)w3;
  *(uint4*)(out + i) = p;
}

// One block = one 128x128 tile of sim = A*A^T (upper triangle, bi<=bj).
// R15 == R9 (verified 69.7 us, absmax 0.0) + XCD-chunked block swizzle.
// MX rounds R10-R14 abandoned: mfma_scale 8-reg operands spill on this
// toolchain regardless of structure/launch_bounds (WRITE_SIZE 840->150 MB,
// never ~65 KB).
// R9 anomaly being attacked here: FETCH_SIZE 62 MB from HBM vs an 8 MB fp8
// matrix == every staging read misses L2+L3 (62 MB at 913 GB/s spans the
// whole 69.7 us kernel -> barrier drains wait on ~900cy HBM latency, which
// is what pins MfmaUtil at 39%).  Cause: consecutive t (same bi panel) are
// round-robined across 8 XCDs -> every A-panel duplicated in all 8 private
// L2s, B-panels stream 8 MB through 4 MB L2 with no reuse order.  Fix:
// bijective XCD-chunk swizzle (2080 = 8*260 exactly): XCD x gets the
// contiguous t-range [x*260, (x+1)*260) -> A-panels L2-resident, B-sweep
// sequential.  (T1; null branch: gload_lds is cache-bypassing -> neutral.)
__global__ __launch_bounds__(256, 3) void gram_loss(const uint8_t* __restrict__ A8,
                                                    const int* __restrict__ targets,
                                                    float* __restrict__ out) {
  __shared__ uint8_t As[128 * 128];   // 16 KB, swizzled [128][8 slots of 16B]
  __shared__ uint8_t Bs[128 * 128];   // 16 KB
  __shared__ int tRow[128];
  __shared__ int tCol[128];
  __shared__ float wsum[4];

  // XCD-chunked bijective remap: blockIdx d -> t, XCDs get contiguous chunks
  int t = (blockIdx.x & 7) * 260 + (blockIdx.x >> 3);   // 2080 = 8 * 260

  // linear t -> (bi, bj) with 0 <= bi <= bj < 64  (fp32 guess + exact fixup)
  int bi = (int)(0.5f * (129.0f - __builtin_sqrtf(129.0f * 129.0f - 8.0f * (float)t)));
  if (bi < 0) bi = 0;
  if (bi > 63) bi = 63;
  while (bi < 63 && ((bi + 1) * (129 - (bi + 1))) / 2 <= t) ++bi;
  while (bi > 0 && (bi * (129 - bi)) / 2 > t) --bi;
  int bj = bi + (t - (bi * (129 - bi)) / 2);

  const int iBase = bi * 128;
  const int jBase = bj * 128;

  const int tid  = threadIdx.x;
  const int wave = tid >> 6;
  const int lane = tid & 63;

  if (tid < 128) tRow[tid] = targets[iBase + tid];
  else           tCol[tid - 128] = targets[jBase + tid - 128];

  // staging: wave w stages rows [w*32, w*32+32) of both tiles, 4 loads each.
  // one load = 64 lanes x 16B = 8 rows x 128B; lane -> row offset lane>>3,
  // SWIZZLED source col-group (lane&7) ^ (lane>>3)  [row&7 == lane>>3 here
  // since each load covers an 8-row-aligned group].
  const int lrow = lane >> 3;                 // 0..7 == row&7
  const int cg   = (lane & 7) ^ lrow;         // swizzled source col-group
  const uint8_t* gA = A8 + (size_t)(iBase + wave * 32 + lrow) * DIM + cg * 16;
  const uint8_t* gB = A8 + (size_t)(jBase + wave * 32 + lrow) * DIM + cg * 16;
  uint8_t* lA = &As[wave * 32 * 128];
  uint8_t* lB = &Bs[wave * 32 * 128];

  const int m0 = (wave >> 1) * 64;
  const int n0 = (wave & 1) * 64;
  const int fr = lane & 15;    // row within 16-block
  const int h  = lane >> 4;    // 0..3: k-subgroup (8 bytes) within 32B k-step
  const int r7 = fr & 7;       // swizzle key (rows are 16-aligned per frag)
  const int hHi = h >> 1;      // which 16B group inside the 32B k-step
  const int hLo = (h & 1) * 8; // byte offset inside the 16B group

  f32x4 acc[4][4] = {};

  for (int kt = 0; kt < NKT; ++kt) {
    __syncthreads();  // previous tile fully consumed
    const int kOff = kt * BK;
#pragma unroll
    for (int l = 0; l < 4; ++l)
      GLOAD_LDS16(gA + (size_t)(l * 8) * DIM + kOff, lA + l * 8 * 128);
#pragma unroll
    for (int l = 0; l < 4; ++l)
      GLOAD_LDS16(gB + (size_t)(l * 8) * DIM + kOff, lB + l * 8 * 128);
    __syncthreads();  // vmcnt(0) drain + barrier: tile landed

    // 4 k-steps of 32; lane reads 8B of A/B per tile-row from swizzled slot
#pragma unroll
    for (int ks = 0; ks < 4; ++ks) {
      const int colOff = (((ks * 2 + hHi) ^ r7) * 16) + hLo;
      long af[4], bf[4];
#pragma unroll
      for (int mi = 0; mi < 4; ++mi)
        af[mi] = *(const long*)&As[(m0 + mi * 16 + fr) * 128 + colOff];
#pragma unroll
      for (int ni = 0; ni < 4; ++ni)
        bf[ni] = *(const long*)&Bs[(n0 + ni * 16 + fr) * 128 + colOff];
#pragma unroll
      for (int mi = 0; mi < 4; ++mi)
#pragma unroll
        for (int ni = 0; ni < 4; ++ni)
          acc[mi][ni] = __builtin_amdgcn_mfma_f32_16x16x32_fp8_fp8(
              af[mi], bf[ni], acc[mi][ni], 0, 0, 0);
    }
  }

  // epilogue: C/D layout col = lane&15, row = (lane>>4)*4 + reg (dtype-indep)
  const int col = lane & 15;
  const int rquad = (lane >> 4) * 4;
  float lsum = 0.0f;
#pragma unroll
  for (int ni = 0; ni < 4; ++ni) {
    const int tj = tCol[n0 + ni * 16 + col];
#pragma unroll
    for (int mi = 0; mi < 4; ++mi) {
#pragma unroll
      for (int r = 0; r < 4; ++r) {
        float s = acc[mi][ni][r];
        int ti = tRow[m0 + mi * 16 + rquad + r];
        lsum += (ti == tj) ? (s < 1.0f ? 1.0f - s : 0.0f)
                           : (s > MARGIN ? s : 0.0f);
      }
    }
  }
  if (bi != bj) lsum *= 2.0f;  // symmetric half counted twice

#pragma unroll
  for (int off = 32; off > 0; off >>= 1) lsum += __shfl_down(lsum, off, 64);
  if (lane == 0) wsum[wave] = lsum;
  __syncthreads();
  if (tid == 0)
    atomicAdd(out, (wsum[0] + wsum[1] + wsum[2] + wsum[3]) * (1.0f / (float)NROWS));
}

extern "C" void kernel_launch(void* const* d_in, const int* in_sizes, int n_in,
                              void* d_out, int out_size, void* d_ws, size_t ws_size,
                              hipStream_t stream) {
  const float* x = (const float*)d_in[0];
  const int* targets = (const int*)d_in[1];
  float* out = (float*)d_out;
  uint8_t* x8 = (uint8_t*)d_ws;  // 8192*1024 = 8 MiB scratch

  cvt_f32_fp8<<<2048, 256, 0, stream>>>(x, x8, out);   // 8388608 = 2048*256*16
  gram_loss<<<2080, 256, 0, stream>>>(x8, targets, out);  // 64*65/2 upper-tri blocks
}